// Round 19
// baseline (110.680 us; speedup 1.0000x reference)
//
#include <hip/hip_runtime.h>
#include <math.h>

#define NH 8            // heads
#define HD 32           // head dim
#define MD 128          // max dist
#define NW 257          // 2*MD+1
#define NWP 272         // padded to 17*16
#define WSM 64          // smoothed PE width
#define NB 4            // batch
#define NL 2048         // length
#define NC 64           // channels
#define NHD 256         // NH*HD
#define SP 40           // padded LDS row stride in bf16 elems (80B)
#define ROWS 128        // output rows per band tile
#define WIN 384         // ROWS + 2*MD
#define WTS 72          // W^T LDS stride in u16
#define TRS 136         // transpose-buffer row stride in u16
// 32^-0.5 * log2(e): scores land in log2 domain -> exp2f directly
#define SC2 0.2550928063161107f

#define NBLK 512        // grid: 512 blocks x 512 threads (co-resident: capacity 1024)
// LDS union: phaseA wt(9216 u16) + tr(8704 u16) = 17920 u16; phaseB qu_sh 15360 u16
#define SMEM_U16 17920

using bf16x8 = __attribute__((ext_vector_type(8))) short;
using f32x4  = __attribute__((ext_vector_type(4))) float;
using i32x4  = __attribute__((ext_vector_type(4))) int;

__device__ __forceinline__ unsigned cvtpk(float lo, float hi) {
  unsigned r;
  asm("v_cvt_pk_bf16_f32 %0, %1, %2" : "=v"(r) : "v"(lo), "v"(hi));
  return r;
}
__device__ __forceinline__ unsigned short f2b(float f) {
  return (unsigned short)cvtpk(f, f);   // RNE bf16, low half
}
__device__ __forceinline__ void stb(unsigned short* p, float f) {
  *p = f2b(f);
}

// ---- single kernel: phaseA (proj GEMM + vv/spe/zero) -> device barrier -> phaseB (band) ----
__global__ __launch_bounds__(512, 4) void fused_kernel(
    const float* __restrict__ x,
    const float* __restrict__ Wq, const float* __restrict__ bq,
    const float* __restrict__ Wk, const float* __restrict__ bk,
    const float* __restrict__ Wv, const float* __restrict__ dpe,
    const float* __restrict__ u_pe, const float* __restrict__ v_pe,
    unsigned short* __restrict__ qu,
    unsigned short* __restrict__ kb, float* __restrict__ vv,
    unsigned short* __restrict__ spt, unsigned* __restrict__ ctr,
    float* __restrict__ out) {
  __shared__ __align__(16) unsigned short smem[SMEM_U16];
  unsigned short* wt = smem;                 // phaseA: [128 col][WTS]
  unsigned short* tr = smem + 128 * WTS;     // phaseA: [64 row][TRS]
  unsigned short* qu_sh = smem;              // phaseB: [WIN][SP]
  float* red = reinterpret_cast<float*>(smem);

  const int rawbid = blockIdx.x;
  const int tid = threadIdx.x;

  // ================= PHASE A =================
  {
    const int bid = rawbid;
    // per-thread proj state (waves 0-3 only)
    bf16x8 a0, a1;
    int c = 0, g = 0, g8 = 0, w = 0, b = 0, l0 = 0, cb = 0;
    bool isQ = true;

    if (tid < 256) {
      const int t = tid;
      const int l64 = t & 63;
      w = t >> 6;
      c = l64 & 15; g = l64 >> 4; g8 = g * 8;
      const int br = bid >> 2;
      const int c0 = (bid & 3) << 7;   // 0,128 -> q cols; 256,384 -> k cols (block-uniform)
      const int r0 = br << 6;
      b = r0 >> 11;
      l0 = r0 & (NL - 1);
      isQ = (c0 < 256);
      const float* Wsrc = isQ ? Wq : Wk;
      cb = isQ ? c0 : c0 - 256;

      // stage W^T tile (128 cols x 64 k) as bf16
#pragma unroll
      for (int i = 0; i < 4; ++i) {
        const int flat = t + i * 256;  // (col4 0..31) x (kpair 0..31)
        const int col4 = flat & 31;
        const int kp = flat >> 5;
        const float4 w0 = *reinterpret_cast<const float4*>(Wsrc + (2 * kp) * NHD + cb + 4 * col4);
        const float4 w1 = *reinterpret_cast<const float4*>(Wsrc + (2 * kp + 1) * NHD + cb + 4 * col4);
        unsigned* wp = reinterpret_cast<unsigned*>(wt);
        wp[(4 * col4 + 0) * (WTS / 2) + kp] = cvtpk(w0.x, w1.x);
        wp[(4 * col4 + 1) * (WTS / 2) + kp] = cvtpk(w0.y, w1.y);
        wp[(4 * col4 + 2) * (WTS / 2) + kp] = cvtpk(w0.z, w1.z);
        wp[(4 * col4 + 3) * (WTS / 2) + kp] = cvtpk(w0.w, w1.w);
      }

      // A fragments: x rows (fp32 -> bf16 in-register)
      const float* xr = x + (size_t)(r0 + 16 * w + c) * NC;
      const float4 x00 = *reinterpret_cast<const float4*>(xr + g8);
      const float4 x01 = *reinterpret_cast<const float4*>(xr + g8 + 4);
      const float4 x10 = *reinterpret_cast<const float4*>(xr + 32 + g8);
      const float4 x11 = *reinterpret_cast<const float4*>(xr + 32 + g8 + 4);
      const i32x4 a0i = {(int)cvtpk(x00.x, x00.y), (int)cvtpk(x00.z, x00.w),
                         (int)cvtpk(x01.x, x01.y), (int)cvtpk(x01.z, x01.w)};
      const i32x4 a1i = {(int)cvtpk(x10.x, x10.y), (int)cvtpk(x10.z, x10.w),
                         (int)cvtpk(x11.x, x11.y), (int)cvtpk(x11.z, x11.w)};
      a0 = __builtin_bit_cast(bf16x8, a0i);
      a1 = __builtin_bit_cast(bf16x8, a1i);
    } else if (tid < 384) {
      // ---- vv: 16 rows x 8 heads per block ----
      const int k = tid - 256;
      const int j = k >> 3, hh = k & 7;
      const int row = bid * 16 + j;
      const float* xr = x + (size_t)row * NC;
      float a = 0.f;
#pragma unroll
      for (int c4 = 0; c4 < NC / 4; ++c4) {
        const float4 xv = *reinterpret_cast<const float4*>(xr + 4 * c4);
        a = fmaf(xv.x, Wv[(4 * c4 + 0) * NH + hh], a);
        a = fmaf(xv.y, Wv[(4 * c4 + 1) * NH + hh], a);
        a = fmaf(xv.z, Wv[(4 * c4 + 2) * NH + hh], a);
        a = fmaf(xv.w, Wv[(4 * c4 + 3) * NH + hh], a);
      }
      const int bb = row >> 11, ll = row & (NL - 1);
      vv[((size_t)hh * NB + bb) * NL + ll] = 1.f / (1.f + __expf(-a));
    } else {
      // ---- spe table slice + d_out zeroing ----
      const int k = tid - 384;
      if (k < 17) {
        const int oz = bid * 17 + k;
        if (oz < NB * NW * NH) out[oz] = 0.f;
      }
#pragma unroll
      for (int it = 0; it < 2; ++it) {
        const int k2 = k + it * 128;
        const int idx = bid * 136 + k2;
        if (k2 < 136 && idx < NH * NWP * HD) {
          const int d = idx & 31;
          const int hm = idx >> 5;
          const int m = hm % NWP;
          const int h = hm / NWP;
          float val = 0.f;
          if (m < NW) {
            float tt = (m + 0.5f) * ((float)WSM / (float)NW) - 0.5f;
            tt = fminf(fmaxf(tt, 0.f), (float)(WSM - 1));
            const int i0 = (int)tt;
            const float f = tt - (float)i0;
            const int i1 = (i0 + 1 < WSM) ? i0 + 1 : WSM - 1;
            const float* bse = dpe + ((size_t)h * HD + d) * WSM;
            val = (bse[i0] * (1.f - f) + bse[i1] * f) * SC2;
          }
          stb(spt + idx, val);
        }
      }
    }

    __syncthreads();   // uniform: all 8 waves

    if (tid < 256) {
      f32x4 acc[8];
#pragma unroll
      for (int tt = 0; tt < 8; ++tt) acc[tt] = {0.f, 0.f, 0.f, 0.f};
      __builtin_amdgcn_s_setprio(1);
#pragma unroll
      for (int tt = 0; tt < 8; ++tt) {
        const bf16x8 b0 = *reinterpret_cast<const bf16x8*>(&wt[(16 * tt + c) * WTS + g8]);
        const bf16x8 b1 = *reinterpret_cast<const bf16x8*>(&wt[(16 * tt + c) * WTS + 32 + g8]);
        acc[tt] = __builtin_amdgcn_mfma_f32_16x16x32_bf16(a0, b0, acc[tt], 0, 0, 0);
        acc[tt] = __builtin_amdgcn_mfma_f32_16x16x32_bf16(a1, b1, acc[tt], 0, 0, 0);
      }
      __builtin_amdgcn_s_setprio(0);
      // transpose-stage: bias + cvt, scatter into tr[row][col]
#pragma unroll
      for (int tt = 0; tt < 8; ++tt) {
        const int col = cb + 16 * tt + c;
        const float bias = isQ ? (bq[col] + u_pe[col]) : bk[col];
#pragma unroll
        for (int r = 0; r < 4; ++r) {
          const float val = isQ ? (acc[tt][r] + bias) : ((acc[tt][r] + bias) * SC2);
          tr[(16 * w + 4 * g + r) * TRS + 16 * tt + c] = f2b(val);
        }
      }
    }

    __syncthreads();   // uniform: all 8 waves (tr visible)

    if (tid < 256) {
      // coalesced readback: 64 rows x 4 heads x 4 chunks of 16B
      unsigned short* dst = isQ ? qu : kb;
#pragma unroll
      for (int i = 0; i < 4; ++i) {
        const int idx = tid + i * 256; // 0..1023
        const int row = idx >> 4;
        const int hd4 = (idx >> 2) & 3;
        const int ch = idx & 3;
        const i32x4 v = *reinterpret_cast<const i32x4*>(&tr[row * TRS + hd4 * 32 + ch * 8]);
        const int col0 = cb + hd4 * 32;
        const int h = col0 >> 5;
        *reinterpret_cast<i32x4*>(dst + (((size_t)h * NB + b) * NL + l0 + row) * HD + ch * 8) = v;
      }
    }
  }

  // ================= device-scope barrier (HBM-resident counter) =================
  __syncthreads();                       // all threads done with phaseA stores
  if (tid == 0) {
    __threadfence();                     // release this block's global writes
    __hip_atomic_fetch_add(ctr, 1u, __ATOMIC_ACQ_REL, __HIP_MEMORY_SCOPE_AGENT);
    while (__hip_atomic_load(ctr, __ATOMIC_ACQUIRE, __HIP_MEMORY_SCOPE_AGENT) < (unsigned)NBLK)
      __builtin_amdgcn_s_sleep(8);
    __threadfence();                     // acquire all blocks' writes
  }
  __syncthreads();

  // ================= PHASE B =================
  {
    // XCD swizzle (T1): each XCD gets 64 consecutive logical bids = 4 full (h,b) panels
    const int bid = (rawbid & 7) * 64 + (rawbid >> 3);   // bijective (512 % 8 == 0)

    const int tile = bid & 15;          // 16 tiles of 128 rows
    const int hb = bid >> 4;            // h*NB + b
    const int b = hb & (NB - 1);
    const int h = hb >> 2;
    const int hc0 = h * HD;
    const int n0 = tile << 7;
    const int jlo = NL - ROWS - n0;     // k rows jlo..jlo+127
    const int l = tid & 63;
    const int w = tid >> 6;             // wave 0..7
    const int c = l & 15;
    const int g = l >> 4;
    const int g8 = g * 8;

    const unsigned short* qu_h = qu + (size_t)hb * NL * HD;
    const unsigned short* k_h  = kb + (size_t)hb * NL * HD;
    const unsigned short* sp_h = spt + (size_t)h * NWP * HD;
    const float* vv_h = vv + (size_t)hb * NL;

    // A fragments + v-gate (global, earliest issue)
    const bf16x8 ak = *reinterpret_cast<const bf16x8*>(k_h + (size_t)(jlo + 16 * w + c) * HD + g8);
    const i32x4 qraw = *reinterpret_cast<const i32x4*>(qu_h + (size_t)(n0 + 127 - 16 * w - c) * HD + g8);
    const f32x4 v4 = *reinterpret_cast<const f32x4*>(vv_h + (n0 + 124 - 16 * w - 4 * g));

    // qu staging loads issued BEFORE the PE chain
    const int wq0_blk = jlo - MD;
    i32x4 stq[3];
#pragma unroll
    for (int it = 0; it < 3; ++it) {    // 384 rows * 4 chunks / 512 threads
      const int p = tid + it * 512;
      const int gr = wq0_blk + (p >> 2);
      i32x4 val = {0, 0, 0, 0};
      if ((unsigned)gr < (unsigned)NL)
        val = *reinterpret_cast<const i32x4*>(qu_h + (size_t)gr * HD + (p & 3) * 8);
      stq[it] = val;
    }

    // reconstruct aqv = bf16( (q+u_pe) + (v_pe - u_pe) ) from the qu row
    const float4 u0 = *reinterpret_cast<const float4*>(u_pe + hc0 + g8);
    const float4 u1 = *reinterpret_cast<const float4*>(u_pe + hc0 + g8 + 4);
    const float4 v0 = *reinterpret_cast<const float4*>(v_pe + hc0 + g8);
    const float4 v1 = *reinterpret_cast<const float4*>(v_pe + hc0 + g8 + 4);
    const float duv[8] = {v0.x - u0.x, v0.y - u0.y, v0.z - u0.z, v0.w - u0.w,
                          v1.x - u1.x, v1.y - u1.y, v1.z - u1.z, v1.w - u1.w};
    i32x4 aqv_i;
#pragma unroll
    for (int k2 = 0; k2 < 4; ++k2) {
      const unsigned uq = (unsigned)qraw[k2];
      const float lo = __builtin_bit_cast(float, uq << 16) + duv[2 * k2];
      const float hi = __builtin_bit_cast(float, uq & 0xffff0000u) + duv[2 * k2 + 1];
      aqv_i[k2] = (int)cvtpk(lo, hi);
    }
    const bf16x8 aqv = __builtin_bit_cast(bf16x8, aqv_i);

    const f32x4 z4 = {0.f, 0.f, 0.f, 0.f};

    // PE term pre-barrier (17 loads, 1 RTT, L1 broadcast across waves)
    f32x4 s[17];
    __builtin_amdgcn_s_setprio(1);
#pragma unroll
    for (int t = 0; t < 17; ++t) {
      const bf16x8 bsp = *reinterpret_cast<const bf16x8*>(sp_h + (size_t)(16 * t + c) * HD + g8);
      s[t] = __builtin_amdgcn_mfma_f32_16x16x32_bf16(aqv, bsp, z4, 0, 0, 0);
    }
    __builtin_amdgcn_s_setprio(0);

    // complete staging: ds_writes + barrier
#pragma unroll
    for (int it = 0; it < 3; ++it) {
      const int p = tid + it * 512;
      *reinterpret_cast<i32x4*>(&qu_sh[(p >> 2) * SP + (p & 3) * 8]) = stq[it];
    }
    __syncthreads();

    // realign constants (m89-verified C/D layout)
    int sl[4]; bool cond[4];
#pragma unroll
    for (int r = 0; r < 4; ++r) {
      sl[r] = 16 * g + ((4 * g + r - c) & 15);
      cond[r] = (4 * g + r) >= c;
    }

    f32x4 shp;
    __builtin_amdgcn_s_setprio(1);
#pragma unroll
    for (int U = 0; U <= 16; ++U) {
      const bf16x8 bqu = *reinterpret_cast<const bf16x8*>(&qu_sh[(16 * w + 16 * U + c) * SP + g8]);
      const f32x4 c1 = __builtin_amdgcn_mfma_f32_16x16x32_bf16(ak, bqu, z4, 0, 0, 0);
      f32x4 shc;
#pragma unroll
      for (int r = 0; r < 4; ++r) shc[r] = __shfl(c1[r], sl[r], 64);
      if (U == 0) {
#pragma unroll
        for (int r = 0; r < 4; ++r)
          s[16][r] = (c == 0) ? (s[16][r] + shc[r]) : -1e30f;  // m=256+c valid only c==0
      } else {
#pragma unroll
        for (int r = 0; r < 4; ++r)
          s[16 - U][r] += cond[r] ? shc[r] : shp[r];
      }
      shp = shc;
    }
    __builtin_amdgcn_s_setprio(0);

    // per-row softmax, no max-subtraction (|scores| ~ 1), exp2 domain
    float wgt[4];
#pragma unroll
    for (int r = 0; r < 4; ++r) {
      float sum = 0.f;
#pragma unroll
      for (int t = 0; t < 17; ++t) {
        const float p = exp2f(s[t][r]);
        s[t][r] = p;
        sum += p;
      }
#pragma unroll
      for (int off = 1; off < 16; off <<= 1) sum += __shfl_xor(sum, off, 16);
      wgt[r] = v4[3 - r] * __builtin_amdgcn_rcpf(sum);  // v[n]/sum, n = n0+127-(16w+4g+r)
    }

    // out[m] += sum_i p * w : regs -> cross-group -> cross-wave (LDS) -> atomics
    __syncthreads();
#pragma unroll
    for (int t = 0; t < 17; ++t) {
      float y = s[t][0] * wgt[0] + s[t][1] * wgt[1] + s[t][2] * wgt[2] + s[t][3] * wgt[3];
      y += __shfl_xor(y, 16, 64);
      y += __shfl_xor(y, 32, 64);
      if (l < 16) red[w * NWP + 16 * t + c] = y;
    }
    __syncthreads();
    for (int m = tid; m < NW; m += 512) {
      float ssum = 0.f;
#pragma unroll
      for (int ww = 0; ww < 8; ++ww) ssum += red[ww * NWP + m];
      atomicAdd(&out[((size_t)b * NW + m) * NH + h], ssum);
    }
  }
}

extern "C" void kernel_launch(void* const* d_in, const int* in_sizes, int n_in,
                              void* d_out, int out_size, void* d_ws, size_t ws_size,
                              hipStream_t stream) {
  const float* x = (const float*)d_in[0];
  const float* Wq = (const float*)d_in[1];
  const float* bq = (const float*)d_in[2];
  const float* Wk = (const float*)d_in[3];
  const float* bk = (const float*)d_in[4];
  const float* Wv = (const float*)d_in[5];
  const float* dpe = (const float*)d_in[6];
  const float* u_pe = (const float*)d_in[7];
  const float* v_pe = (const float*)d_in[8];
  float* out = (float*)d_out;

  const size_t qk_elems = (size_t)NH * NB * NL * HD;  // 2,097,152
  unsigned* ctr = (unsigned*)d_ws;                    // barrier counter (reset each call)
  float* vv = (float*)d_ws + 16;                      // 65,536 f32
  unsigned short* qu = (unsigned short*)(vv + (size_t)NH * NB * NL);
  unsigned short* kb = qu + qk_elems;
  unsigned short* spt = kb + qk_elems;                // 8*272*32

  hipMemsetAsync(ctr, 0, sizeof(unsigned), stream);
  hipLaunchKernelGGL(fused_kernel, dim3(NBLK), dim3(512), 0, stream,
                     x, Wq, bq, Wk, bk, Wv, dpe, u_pe, v_pe, qu, kb, vv, spt, ctr, out);
}

// Round 20
// 31.671 us; speedup vs baseline: 3.4947x; 3.4947x over previous
//
#include <hip/hip_runtime.h>
#include <math.h>

#define NH 8            // heads
#define HD 32           // head dim
#define MD 128          // max dist
#define NW 257          // 2*MD+1
#define NWP 272         // padded to 17*16
#define WSM 64          // smoothed PE width
#define NB 4            // batch
#define NL 2048         // length
#define NC 64           // channels
#define NHD 256         // NH*HD
#define SP 40           // padded LDS row stride in bf16 elems (80B)
#define ROWS 128        // output rows per band block
#define WIN 384         // ROWS + 2*MD
#define WTS 72          // W^T LDS stride in u16 (144B, 2-way bank aliasing = free)
#define TRS 136         // transpose-buffer row stride in u16 (272B, padded)
// 32^-0.5 * log2(e): scores land in log2 domain -> exp2f directly
#define SC2 0.2550928063161107f

#define NBLK 512        // both kernels: 512 blocks x 512 threads

using bf16x8 = __attribute__((ext_vector_type(8))) short;
using f32x4  = __attribute__((ext_vector_type(4))) float;
using i32x4  = __attribute__((ext_vector_type(4))) int;

__device__ __forceinline__ unsigned cvtpk(float lo, float hi) {
  unsigned r;
  asm("v_cvt_pk_bf16_f32 %0, %1, %2" : "=v"(r) : "v"(lo), "v"(hi));
  return r;
}
__device__ __forceinline__ unsigned short f2b(float f) {
  return (unsigned short)cvtpk(f, f);   // RNE bf16, low half
}
__device__ __forceinline__ void stb(unsigned short* p, float f) {
  *p = f2b(f);
}

// ================= PHASE A: proj GEMM (waves 0-3) + vv/spe/zero (waves 4-7) =================
// Writes qu = bf16(q + u_pe) and kb = bf16(k)*SC2; epilogue goes through an LDS transpose
// so global stores are coalesced dwordx4 instead of 32 scalar u16 per thread.
__global__ __launch_bounds__(512, 4) void phaseA_kernel(
    const float* __restrict__ x,
    const float* __restrict__ Wq, const float* __restrict__ bq,
    const float* __restrict__ Wk, const float* __restrict__ bk,
    const float* __restrict__ Wv, const float* __restrict__ dpe,
    const float* __restrict__ u_pe,
    unsigned short* __restrict__ qu,
    unsigned short* __restrict__ kb, float* __restrict__ vv,
    unsigned short* __restrict__ spt, float* __restrict__ out) {
  __shared__ __align__(16) unsigned short wt[128 * WTS];  // 18 KB W^T tile
  __shared__ __align__(16) unsigned short tr[64 * TRS];   // 17 KB transpose buffer
  const int bid = blockIdx.x;
  const int tid = threadIdx.x;

  // per-thread proj state (waves 0-3 only)
  bf16x8 a0, a1;
  int c = 0, g = 0, g8 = 0, w = 0, b = 0, l0 = 0, cb = 0;
  bool isQ = true;

  if (tid < 256) {
    const int t = tid;
    const int l64 = t & 63;
    w = t >> 6;
    c = l64 & 15; g = l64 >> 4; g8 = g * 8;
    const int br = bid >> 2;
    const int c0 = (bid & 3) << 7;     // 0,128 -> q cols; 256,384 -> k cols (block-uniform)
    const int r0 = br << 6;
    b = r0 >> 11;
    l0 = r0 & (NL - 1);
    isQ = (c0 < 256);
    const float* Wsrc = isQ ? Wq : Wk;
    cb = isQ ? c0 : c0 - 256;

    // stage W^T tile (128 cols x 64 k) as bf16: coalesced float4 loads + packed writes
#pragma unroll
    for (int i = 0; i < 4; ++i) {
      const int flat = t + i * 256;    // 0..1023 = (col4 0..31) x (kpair 0..31)
      const int col4 = flat & 31;
      const int kp = flat >> 5;
      const float4 w0 = *reinterpret_cast<const float4*>(Wsrc + (2 * kp) * NHD + cb + 4 * col4);
      const float4 w1 = *reinterpret_cast<const float4*>(Wsrc + (2 * kp + 1) * NHD + cb + 4 * col4);
      unsigned* wp = reinterpret_cast<unsigned*>(wt);
      wp[(4 * col4 + 0) * (WTS / 2) + kp] = cvtpk(w0.x, w1.x);
      wp[(4 * col4 + 1) * (WTS / 2) + kp] = cvtpk(w0.y, w1.y);
      wp[(4 * col4 + 2) * (WTS / 2) + kp] = cvtpk(w0.z, w1.z);
      wp[(4 * col4 + 3) * (WTS / 2) + kp] = cvtpk(w0.w, w1.w);
    }

    // A fragments: x rows (fp32 -> bf16 in-register); lane c = row, g = k-chunk
    const float* xr = x + (size_t)(r0 + 16 * w + c) * NC;
    const float4 x00 = *reinterpret_cast<const float4*>(xr + g8);
    const float4 x01 = *reinterpret_cast<const float4*>(xr + g8 + 4);
    const float4 x10 = *reinterpret_cast<const float4*>(xr + 32 + g8);
    const float4 x11 = *reinterpret_cast<const float4*>(xr + 32 + g8 + 4);
    const i32x4 a0i = {(int)cvtpk(x00.x, x00.y), (int)cvtpk(x00.z, x00.w),
                       (int)cvtpk(x01.x, x01.y), (int)cvtpk(x01.z, x01.w)};
    const i32x4 a1i = {(int)cvtpk(x10.x, x10.y), (int)cvtpk(x10.z, x10.w),
                       (int)cvtpk(x11.x, x11.y), (int)cvtpk(x11.z, x11.w)};
    a0 = __builtin_bit_cast(bf16x8, a0i);
    a1 = __builtin_bit_cast(bf16x8, a1i);
  } else if (tid < 384) {
    // ---- vv: 16 rows x 8 heads per block ----
    const int k = tid - 256;
    const int j = k >> 3, hh = k & 7;
    const int row = bid * 16 + j;
    const float* xr = x + (size_t)row * NC;
    float a = 0.f;
#pragma unroll
    for (int c4 = 0; c4 < NC / 4; ++c4) {
      const float4 xv = *reinterpret_cast<const float4*>(xr + 4 * c4);
      a = fmaf(xv.x, Wv[(4 * c4 + 0) * NH + hh], a);
      a = fmaf(xv.y, Wv[(4 * c4 + 1) * NH + hh], a);
      a = fmaf(xv.z, Wv[(4 * c4 + 2) * NH + hh], a);
      a = fmaf(xv.w, Wv[(4 * c4 + 3) * NH + hh], a);
    }
    const int bb = row >> 11, ll = row & (NL - 1);
    vv[((size_t)hh * NB + bb) * NL + ll] = 1.f / (1.f + __expf(-a));
  } else {
    // ---- spe table slice + d_out zeroing ----
    const int k = tid - 384;
    if (k < 17) {
      const int oz = bid * 17 + k;
      if (oz < NB * NW * NH) out[oz] = 0.f;
    }
#pragma unroll
    for (int it = 0; it < 2; ++it) {
      const int k2 = k + it * 128;
      const int idx = bid * 136 + k2;
      if (k2 < 136 && idx < NH * NWP * HD) {
        const int d = idx & 31;
        const int hm = idx >> 5;
        const int m = hm % NWP;
        const int h = hm / NWP;
        float val = 0.f;
        if (m < NW) {
          float tt = (m + 0.5f) * ((float)WSM / (float)NW) - 0.5f;
          tt = fminf(fmaxf(tt, 0.f), (float)(WSM - 1));
          const int i0 = (int)tt;
          const float f = tt - (float)i0;
          const int i1 = (i0 + 1 < WSM) ? i0 + 1 : WSM - 1;
          const float* bse = dpe + ((size_t)h * HD + d) * WSM;
          val = (bse[i0] * (1.f - f) + bse[i1] * f) * SC2;
        }
        stb(spt + idx, val);
      }
    }
  }

  __syncthreads();   // uniform: all 8 waves

  if (tid < 256) {
    f32x4 acc[8];
#pragma unroll
    for (int tt = 0; tt < 8; ++tt) acc[tt] = {0.f, 0.f, 0.f, 0.f};
    __builtin_amdgcn_s_setprio(1);
#pragma unroll
    for (int tt = 0; tt < 8; ++tt) {
      const bf16x8 b0 = *reinterpret_cast<const bf16x8*>(&wt[(16 * tt + c) * WTS + g8]);
      const bf16x8 b1 = *reinterpret_cast<const bf16x8*>(&wt[(16 * tt + c) * WTS + 32 + g8]);
      acc[tt] = __builtin_amdgcn_mfma_f32_16x16x32_bf16(a0, b0, acc[tt], 0, 0, 0);
      acc[tt] = __builtin_amdgcn_mfma_f32_16x16x32_bf16(a1, b1, acc[tt], 0, 0, 0);
    }
    __builtin_amdgcn_s_setprio(0);
    // transpose-stage: bias + cvt, scatter into tr[row][col] (2-way bank alias = free)
#pragma unroll
    for (int tt = 0; tt < 8; ++tt) {
      const int col = cb + 16 * tt + c;
      const float bias = isQ ? (bq[col] + u_pe[col]) : bk[col];
#pragma unroll
      for (int r = 0; r < 4; ++r) {
        const float val = isQ ? (acc[tt][r] + bias) : ((acc[tt][r] + bias) * SC2);
        tr[(16 * w + 4 * g + r) * TRS + 16 * tt + c] = f2b(val);
      }
    }
  }

  __syncthreads();   // uniform: all 8 waves (tr visible)

  if (tid < 256) {
    // coalesced readback: 64 rows x 4 heads x 4 chunks of 16B = 1024 dwordx4
    unsigned short* dst = isQ ? qu : kb;
#pragma unroll
    for (int i = 0; i < 4; ++i) {
      const int idx = tid + i * 256;   // 0..1023
      const int row = idx >> 4;
      const int hd4 = (idx >> 2) & 3;
      const int ch = idx & 3;
      const i32x4 v = *reinterpret_cast<const i32x4*>(&tr[row * TRS + hd4 * 32 + ch * 8]);
      const int col0 = cb + hd4 * 32;
      const int h = col0 >> 5;
      *reinterpret_cast<i32x4*>(dst + (((size_t)h * NB + b) * NL + l0 + row) * HD + ch * 8) = v;
    }
  }
}

// ================= PHASE B: band + PE + softmax + gate + reduce =================
__global__ __launch_bounds__(512, 4) void phaseB_kernel(
    const unsigned short* __restrict__ qu,
    const unsigned short* __restrict__ kb, const float* __restrict__ vv,
    const unsigned short* __restrict__ spt,
    const float* __restrict__ u_pe, const float* __restrict__ v_pe,
    float* __restrict__ out) {
  __shared__ __align__(16) unsigned short qu_sh[WIN * SP];
  float* red = reinterpret_cast<float*>(qu_sh);

  // XCD swizzle (T1): each XCD gets 64 consecutive logical bids = 4 full (h,b) panels.
  const int raw = blockIdx.x;
  const int bid = (raw & 7) * 64 + (raw >> 3);   // bijective (512 % 8 == 0)
  const int tid = threadIdx.x;

  const int tile = bid & 15;          // 16 tiles of 128 rows
  const int hb = bid >> 4;            // h*NB + b
  const int b = hb & (NB - 1);
  const int h = hb >> 2;
  const int hc0 = h * HD;
  const int n0 = tile << 7;
  const int jlo = NL - ROWS - n0;     // k rows jlo..jlo+127
  const int l = tid & 63;
  const int w = tid >> 6;             // wave 0..7
  const int c = l & 15;
  const int g = l >> 4;
  const int g8 = g * 8;

  const unsigned short* qu_h = qu + (size_t)hb * NL * HD;
  const unsigned short* k_h  = kb + (size_t)hb * NL * HD;
  const unsigned short* sp_h = spt + (size_t)h * NWP * HD;
  const float* vv_h = vv + (size_t)hb * NL;

  // A fragments + v-gate (global, earliest issue)
  const bf16x8 ak = *reinterpret_cast<const bf16x8*>(k_h + (size_t)(jlo + 16 * w + c) * HD + g8);
  const i32x4 qraw = *reinterpret_cast<const i32x4*>(qu_h + (size_t)(n0 + 127 - 16 * w - c) * HD + g8);
  const f32x4 v4 = *reinterpret_cast<const f32x4*>(vv_h + (n0 + 124 - 16 * w - 4 * g));

  // qu staging loads issued BEFORE the PE chain (their RTT completes under PE compute)
  const int wq0_blk = jlo - MD;
  i32x4 stq[3];
#pragma unroll
  for (int it = 0; it < 3; ++it) {    // 384 rows * 4 chunks / 512 threads
    const int p = tid + it * 512;
    const int gr = wq0_blk + (p >> 2);
    i32x4 val = {0, 0, 0, 0};
    if ((unsigned)gr < (unsigned)NL)
      val = *reinterpret_cast<const i32x4*>(qu_h + (size_t)gr * HD + (p & 3) * 8);
    stq[it] = val;
  }

  // reconstruct aqv = bf16( (q+u_pe) + (v_pe - u_pe) ) from the qu row (qv tensor removed)
  const float4 u0 = *reinterpret_cast<const float4*>(u_pe + hc0 + g8);
  const float4 u1 = *reinterpret_cast<const float4*>(u_pe + hc0 + g8 + 4);
  const float4 v0 = *reinterpret_cast<const float4*>(v_pe + hc0 + g8);
  const float4 v1 = *reinterpret_cast<const float4*>(v_pe + hc0 + g8 + 4);
  const float duv[8] = {v0.x - u0.x, v0.y - u0.y, v0.z - u0.z, v0.w - u0.w,
                        v1.x - u1.x, v1.y - u1.y, v1.z - u1.z, v1.w - u1.w};
  i32x4 aqv_i;
#pragma unroll
  for (int k2 = 0; k2 < 4; ++k2) {
    const unsigned uq = (unsigned)qraw[k2];
    const float lo = __builtin_bit_cast(float, uq << 16) + duv[2 * k2];
    const float hi = __builtin_bit_cast(float, uq & 0xffff0000u) + duv[2 * k2 + 1];
    aqv_i[k2] = (int)cvtpk(lo, hi);
  }
  const bf16x8 aqv = __builtin_bit_cast(bf16x8, aqv_i);

  const f32x4 z4 = {0.f, 0.f, 0.f, 0.f};

  // PE term pre-barrier (17 loads, 1 RTT, L1 broadcast across waves)
  f32x4 s[17];
  __builtin_amdgcn_s_setprio(1);
#pragma unroll
  for (int t = 0; t < 17; ++t) {
    const bf16x8 bsp = *reinterpret_cast<const bf16x8*>(sp_h + (size_t)(16 * t + c) * HD + g8);
    s[t] = __builtin_amdgcn_mfma_f32_16x16x32_bf16(aqv, bsp, z4, 0, 0, 0);
  }
  __builtin_amdgcn_s_setprio(0);

  // complete staging: ds_writes + barrier
#pragma unroll
  for (int it = 0; it < 3; ++it) {
    const int p = tid + it * 512;
    *reinterpret_cast<i32x4*>(&qu_sh[(p >> 2) * SP + (p & 3) * 8]) = stq[it];
  }
  __syncthreads();

  // realign constants (m89-verified C/D layout)
  int sl[4]; bool cond[4];
#pragma unroll
  for (int r = 0; r < 4; ++r) {
    sl[r] = 16 * g + ((4 * g + r - c) & 15);
    cond[r] = (4 * g + r) >= c;
  }

  f32x4 shp;
  __builtin_amdgcn_s_setprio(1);
#pragma unroll
  for (int U = 0; U <= 16; ++U) {
    const bf16x8 bqu = *reinterpret_cast<const bf16x8*>(&qu_sh[(16 * w + 16 * U + c) * SP + g8]);
    const f32x4 c1 = __builtin_amdgcn_mfma_f32_16x16x32_bf16(ak, bqu, z4, 0, 0, 0);
    f32x4 shc;
#pragma unroll
    for (int r = 0; r < 4; ++r) shc[r] = __shfl(c1[r], sl[r], 64);
    if (U == 0) {
#pragma unroll
      for (int r = 0; r < 4; ++r)
        s[16][r] = (c == 0) ? (s[16][r] + shc[r]) : -1e30f;  // m=256+c valid only c==0
    } else {
#pragma unroll
      for (int r = 0; r < 4; ++r)
        s[16 - U][r] += cond[r] ? shc[r] : shp[r];
    }
    shp = shc;
  }
  __builtin_amdgcn_s_setprio(0);

  // per-row softmax, no max-subtraction (|scores| ~ 1), exp2 domain
  float wgt[4];
#pragma unroll
  for (int r = 0; r < 4; ++r) {
    float sum = 0.f;
#pragma unroll
    for (int t = 0; t < 17; ++t) {
      const float p = exp2f(s[t][r]);
      s[t][r] = p;
      sum += p;
    }
#pragma unroll
    for (int off = 1; off < 16; off <<= 1) sum += __shfl_xor(sum, off, 16);
    wgt[r] = v4[3 - r] * __builtin_amdgcn_rcpf(sum);  // v[n]/sum, n = n0+127-(16w+4g+r)
  }

  // out[m] += sum_i p * w : regs -> cross-group -> cross-wave (LDS) -> atomics
  __syncthreads();
#pragma unroll
  for (int t = 0; t < 17; ++t) {
    float y = s[t][0] * wgt[0] + s[t][1] * wgt[1] + s[t][2] * wgt[2] + s[t][3] * wgt[3];
    y += __shfl_xor(y, 16, 64);
    y += __shfl_xor(y, 32, 64);
    if (l < 16) red[w * NWP + 16 * t + c] = y;
  }
  __syncthreads();
  for (int m = tid; m < NW; m += 512) {
    float ssum = 0.f;
#pragma unroll
    for (int ww = 0; ww < 8; ++ww) ssum += red[ww * NWP + m];
    atomicAdd(&out[((size_t)b * NW + m) * NH + h], ssum);
  }
}

extern "C" void kernel_launch(void* const* d_in, const int* in_sizes, int n_in,
                              void* d_out, int out_size, void* d_ws, size_t ws_size,
                              hipStream_t stream) {
  const float* x = (const float*)d_in[0];
  const float* Wq = (const float*)d_in[1];
  const float* bq = (const float*)d_in[2];
  const float* Wk = (const float*)d_in[3];
  const float* bk = (const float*)d_in[4];
  const float* Wv = (const float*)d_in[5];
  const float* dpe = (const float*)d_in[6];
  const float* u_pe = (const float*)d_in[7];
  const float* v_pe = (const float*)d_in[8];
  float* out = (float*)d_out;

  const size_t qk_elems = (size_t)NH * NB * NL * HD;  // 2,097,152
  float* vv = (float*)d_ws;                           // 65,536 f32
  unsigned short* qu = (unsigned short*)(vv + (size_t)NH * NB * NL);
  unsigned short* kb = qu + qk_elems;
  unsigned short* spt = kb + qk_elems;                // 8*272*32

  hipLaunchKernelGGL(phaseA_kernel, dim3(NBLK), dim3(512), 0, stream,
                     x, Wq, bq, Wk, bk, Wv, dpe, u_pe, qu, kb, vv, spt, out);
  hipLaunchKernelGGL(phaseB_kernel, dim3(NBLK), dim3(512), 0, stream,
                     qu, kb, vv, spt, u_pe, v_pe, out);
}